// Round 1
// baseline (77.044 us; speedup 1.0000x reference)
//
#include <hip/hip_runtime.h>
#include <math.h>

#define B_    128
#define S_    2048
#define FEAT_ 512
#define DK_   64
#define NSPLIT 16
#define CHUNK  (S_ / NSPLIT)   // 128 rows per split

// ---------------------------------------------------------------------------
// Kernel 1: v[b,f] = sum_d W_K[f,d] * (sum_g input_q[b,g] * W_Q[g,d])
// One block per batch. Tiny (128 blocks, dominated by nothing).
// ---------------------------------------------------------------------------
__global__ __launch_bounds__(256) void qv_kernel(
    const float* __restrict__ input_q, const float* __restrict__ W_Q,
    const float* __restrict__ W_K, float* __restrict__ v) {
  int b = blockIdx.x;
  int tid = threadIdx.x;
  __shared__ float xq[FEAT_];
  __shared__ float qs[DK_];
  for (int f = tid; f < FEAT_; f += 256) xq[f] = input_q[b * FEAT_ + f];
  __syncthreads();
  if (tid < DK_) {
    float s = 0.f;
    for (int f = 0; f < FEAT_; ++f) s += xq[f] * W_Q[f * DK_ + tid];
    qs[tid] = s;
  }
  __syncthreads();
  for (int f = tid; f < FEAT_; f += 256) {
    float s = 0.f;
#pragma unroll
    for (int d = 0; d < DK_; ++d) s += W_K[f * DK_ + d] * qs[d];
    v[b * FEAT_ + f] = s;
  }
}

// ---------------------------------------------------------------------------
// Kernel 2: one streaming pass over input_k rows s in [split*CHUNK, L),
// online softmax + context accumulation. Each wave owns rows strided by 4;
// lane owns f = lane*4..lane*4+3 and 256+lane*4..+3 (two contiguous float4
// halves -> each global load instr covers a contiguous 1 KB).
// Writes per-(b,split) partial: m, l, acc[512].
// ---------------------------------------------------------------------------
__global__ __launch_bounds__(256) void pass_kernel(
    const float* __restrict__ input_k, const int* __restrict__ ctx,
    const float* __restrict__ v, float* __restrict__ pm,
    float* __restrict__ pl, float* __restrict__ pacc) {
  int split = blockIdx.x;
  int b = blockIdx.y;
  int L = ctx[b];
  int s0 = split * CHUNK;
  int s1 = min(s0 + CHUNK, L);
  int tid = threadIdx.x, wave = tid >> 6, lane = tid & 63;

  const float* vb = v + b * FEAT_;
  float4 v0 = *(const float4*)(vb + lane * 4);
  float4 v1 = *(const float4*)(vb + 256 + lane * 4);

  float m = -INFINITY, l = 0.f;
  float4 a0 = make_float4(0.f, 0.f, 0.f, 0.f);
  float4 a1 = make_float4(0.f, 0.f, 0.f, 0.f);

  for (int s = s0 + wave; s < s1; s += 4) {
    const float* row = input_k + ((size_t)b * S_ + s) * FEAT_;
    float4 x0 = *(const float4*)(row + lane * 4);
    float4 x1 = *(const float4*)(row + 256 + lane * 4);
    float p = x0.x * v0.x + x0.y * v0.y + x0.z * v0.z + x0.w * v0.w +
              x1.x * v1.x + x1.y * v1.y + x1.z * v1.z + x1.w * v1.w;
#pragma unroll
    for (int off = 32; off; off >>= 1) p += __shfl_xor(p, off, 64);
    float mn = fmaxf(m, p);
    float sc = __expf(m - mn);   // first iter: exp(-inf)=0
    float w  = __expf(p - mn);
    l = l * sc + w;
    a0.x = fmaf(a0.x, sc, w * x0.x);
    a0.y = fmaf(a0.y, sc, w * x0.y);
    a0.z = fmaf(a0.z, sc, w * x0.z);
    a0.w = fmaf(a0.w, sc, w * x0.w);
    a1.x = fmaf(a1.x, sc, w * x1.x);
    a1.y = fmaf(a1.y, sc, w * x1.y);
    a1.z = fmaf(a1.z, sc, w * x1.z);
    a1.w = fmaf(a1.w, sc, w * x1.w);
    m = mn;
  }

  // cross-wave combine in LDS
  __shared__ float sm[4], sl[4];
  __shared__ float sa[4][FEAT_];
  if (lane == 0) { sm[wave] = m; sl[wave] = l; }
  *(float4*)&sa[wave][lane * 4] = a0;
  *(float4*)&sa[wave][256 + lane * 4] = a1;
  __syncthreads();

  float M = fmaxf(fmaxf(sm[0], sm[1]), fmaxf(sm[2], sm[3]));
  int idx = b * NSPLIT + split;
  if (M == -INFINITY) {  // no active rows in this split (uniform branch)
    if (tid == 0) { pm[idx] = -INFINITY; pl[idx] = 0.f; }
    for (int f = tid; f < FEAT_; f += 256) pacc[(size_t)idx * FEAT_ + f] = 0.f;
    return;
  }
  float e0 = __expf(sm[0] - M), e1 = __expf(sm[1] - M);
  float e2 = __expf(sm[2] - M), e3 = __expf(sm[3] - M);
  if (tid == 0) {
    pm[idx] = M;
    pl[idx] = e0 * sl[0] + e1 * sl[1] + e2 * sl[2] + e3 * sl[3];
  }
  for (int f = tid; f < FEAT_; f += 256)
    pacc[(size_t)idx * FEAT_ + f] =
        e0 * sa[0][f] + e1 * sa[1][f] + e2 * sa[2][f] + e3 * sa[3][f];
}

// ---------------------------------------------------------------------------
// Kernel 3: combine NSPLIT partials per batch, normalize, zero L==0 rows.
// ---------------------------------------------------------------------------
__global__ __launch_bounds__(256) void combine_kernel(
    const float* __restrict__ pm, const float* __restrict__ pl,
    const float* __restrict__ pacc, float* __restrict__ out) {
  int b = blockIdx.x;
  int tid = threadIdx.x;
  __shared__ float e[NSPLIT];
  __shared__ float inv_s;
  if (tid == 0) {
    float M = -INFINITY;
    for (int i = 0; i < NSPLIT; ++i) M = fmaxf(M, pm[b * NSPLIT + i]);
    float lt = 0.f;
    for (int i = 0; i < NSPLIT; ++i) {
      float ei = (M == -INFINITY) ? 0.f : __expf(pm[b * NSPLIT + i] - M);
      e[i] = ei;
      lt += ei * pl[b * NSPLIT + i];
    }
    inv_s = (lt > 0.f) ? 1.f / lt : 0.f;   // lt==0 <=> context_len==0 -> zeros
  }
  __syncthreads();
  float inv = inv_s;
  for (int f = tid; f < FEAT_; f += 256) {
    float s = 0.f;
#pragma unroll
    for (int i = 0; i < NSPLIT; ++i)
      s += e[i] * pacc[((size_t)(b * NSPLIT + i)) * FEAT_ + f];
    out[b * FEAT_ + f] = s * inv;
  }
}

extern "C" void kernel_launch(void* const* d_in, const int* in_sizes, int n_in,
                              void* d_out, int out_size, void* d_ws, size_t ws_size,
                              hipStream_t stream) {
  const float* input_k = (const float*)d_in[0];
  const float* input_q = (const float*)d_in[1];
  const int*   ctx     = (const int*)d_in[2];
  const float* W_K     = (const float*)d_in[3];
  const float* W_Q     = (const float*)d_in[4];
  float* out = (float*)d_out;

  char* ws = (char*)d_ws;
  float* v    = (float*)ws;                                   // B*FEAT
  float* pm   = (float*)(ws + (size_t)B_ * FEAT_ * sizeof(float));
  float* pl   = pm + B_ * NSPLIT;
  float* pacc = pl + B_ * NSPLIT;                             // B*NSPLIT*FEAT

  qv_kernel<<<B_, 256, 0, stream>>>(input_q, W_Q, W_K, v);
  pass_kernel<<<dim3(NSPLIT, B_), 256, 0, stream>>>(input_k, ctx, v, pm, pl, pacc);
  combine_kernel<<<B_, 256, 0, stream>>>(pm, pl, pacc, out);
}

// Round 2
// 66.058 us; speedup vs baseline: 1.1663x; 1.1663x over previous
//
#include <hip/hip_runtime.h>
#include <math.h>

#define B_    128
#define S_    2048
#define FEAT_ 512
#define DK_   64
#define NSPLIT 32
#define CHUNK  (S_ / NSPLIT)   // 64 rows per split

// ---------------------------------------------------------------------------
// Kernel 1: v[b,f] = sum_d W_K[f,d] * (sum_g input_q[b,g] * W_Q[g,d])
// One block per batch.
// ---------------------------------------------------------------------------
__global__ __launch_bounds__(256) void qv_kernel(
    const float* __restrict__ input_q, const float* __restrict__ W_Q,
    const float* __restrict__ W_K, float* __restrict__ v) {
  int b = blockIdx.x;
  int tid = threadIdx.x;
  __shared__ float xq[FEAT_];
  __shared__ float part[4][DK_];
  __shared__ float qs[DK_];
  for (int f = tid; f < FEAT_; f += 256) xq[f] = input_q[b * FEAT_ + f];
  __syncthreads();
  {
    int d = tid & 63, c = tid >> 6;           // 4 chunks of 128 features
    float s = 0.f;
    int f0 = c * 128;
    for (int f = f0; f < f0 + 128; ++f) s = fmaf(xq[f], W_Q[f * DK_ + d], s);
    part[c][d] = s;
  }
  __syncthreads();
  if (tid < DK_)
    qs[tid] = part[0][tid] + part[1][tid] + part[2][tid] + part[3][tid];
  __syncthreads();
  for (int f = tid; f < FEAT_; f += 256) {
    const float4* wk = (const float4*)(W_K + f * DK_);
    float s = 0.f;
#pragma unroll
    for (int d4 = 0; d4 < DK_ / 4; ++d4) {
      float4 w = wk[d4];
      s = fmaf(w.x, qs[d4 * 4 + 0], s);
      s = fmaf(w.y, qs[d4 * 4 + 1], s);
      s = fmaf(w.z, qs[d4 * 4 + 2], s);
      s = fmaf(w.w, qs[d4 * 4 + 3], s);
    }
    v[b * FEAT_ + f] = s;
  }
}

__device__ __forceinline__ float dot8(float4 x0, float4 x1, float4 v0, float4 v1) {
  float p = x0.x * v0.x;
  p = fmaf(x0.y, v0.y, p);
  p = fmaf(x0.z, v0.z, p);
  p = fmaf(x0.w, v0.w, p);
  p = fmaf(x1.x, v1.x, p);
  p = fmaf(x1.y, v1.y, p);
  p = fmaf(x1.z, v1.z, p);
  p = fmaf(x1.w, v1.w, p);
  return p;
}

// ---------------------------------------------------------------------------
// Kernel 2: streaming pass, online softmax + context accumulation.
// 4 waves/block; wave owns rows strided by 4; unrolled 4 rows/iteration so
// 8 dwordx4 loads (8 KB/wave) are in flight and the 24 shfl reductions of
// 4 independent rows overlap in the LDS pipe.
// ---------------------------------------------------------------------------
__global__ __launch_bounds__(256) void pass_kernel(
    const float* __restrict__ input_k, const int* __restrict__ ctx,
    const float* __restrict__ v, float* __restrict__ pm,
    float* __restrict__ pl, float* __restrict__ pacc) {
  int split = blockIdx.x;
  int b = blockIdx.y;
  int L = ctx[b];
  int s0 = split * CHUNK;
  int s1 = min(s0 + CHUNK, L);
  int tid = threadIdx.x, wave = tid >> 6, lane = tid & 63;

  const float* vb = v + b * FEAT_;
  float4 v0 = *(const float4*)(vb + lane * 4);
  float4 v1 = *(const float4*)(vb + 256 + lane * 4);

  float m = -INFINITY, l = 0.f;
  float4 a0 = make_float4(0.f, 0.f, 0.f, 0.f);
  float4 a1 = make_float4(0.f, 0.f, 0.f, 0.f);

  const float* base = input_k + (size_t)b * S_ * FEAT_;
  int s = s0 + wave;

  // main loop: 4 rows per iteration
  for (; s + 12 < s1; s += 16) {
    const float* r0 = base + (size_t)s * FEAT_;
    const float* r1 = r0 + 4 * FEAT_;
    const float* r2 = r0 + 8 * FEAT_;
    const float* r3 = r0 + 12 * FEAT_;
    float4 x00 = *(const float4*)(r0 + lane * 4);
    float4 x01 = *(const float4*)(r0 + 256 + lane * 4);
    float4 x10 = *(const float4*)(r1 + lane * 4);
    float4 x11 = *(const float4*)(r1 + 256 + lane * 4);
    float4 x20 = *(const float4*)(r2 + lane * 4);
    float4 x21 = *(const float4*)(r2 + 256 + lane * 4);
    float4 x30 = *(const float4*)(r3 + lane * 4);
    float4 x31 = *(const float4*)(r3 + 256 + lane * 4);

    float p0 = dot8(x00, x01, v0, v1);
    float p1 = dot8(x10, x11, v0, v1);
    float p2 = dot8(x20, x21, v0, v1);
    float p3 = dot8(x30, x31, v0, v1);
#pragma unroll
    for (int off = 32; off; off >>= 1) {
      p0 += __shfl_xor(p0, off, 64);
      p1 += __shfl_xor(p1, off, 64);
      p2 += __shfl_xor(p2, off, 64);
      p3 += __shfl_xor(p3, off, 64);
    }
    float mn = fmaxf(fmaxf(fmaxf(p0, p1), fmaxf(p2, p3)), m);
    float sc = __expf(m - mn);   // first iter: exp(-inf)=0
    float w0 = __expf(p0 - mn), w1 = __expf(p1 - mn);
    float w2 = __expf(p2 - mn), w3 = __expf(p3 - mn);
    l = fmaf(l, sc, (w0 + w1) + (w2 + w3));
#define ACC(comp, f0c, f1c, f2c, f3c)                       \
    {                                                        \
      float t = comp * sc;                                   \
      t = fmaf(w0, f0c, t);                                  \
      t = fmaf(w1, f1c, t);                                  \
      t = fmaf(w2, f2c, t);                                  \
      t = fmaf(w3, f3c, t);                                  \
      comp = t;                                              \
    }
    ACC(a0.x, x00.x, x10.x, x20.x, x30.x)
    ACC(a0.y, x00.y, x10.y, x20.y, x30.y)
    ACC(a0.z, x00.z, x10.z, x20.z, x30.z)
    ACC(a0.w, x00.w, x10.w, x20.w, x30.w)
    ACC(a1.x, x01.x, x11.x, x21.x, x31.x)
    ACC(a1.y, x01.y, x11.y, x21.y, x31.y)
    ACC(a1.z, x01.z, x11.z, x21.z, x31.z)
    ACC(a1.w, x01.w, x11.w, x21.w, x31.w)
#undef ACC
    m = mn;
  }

  // tail: single row per iteration
  for (; s < s1; s += 4) {
    const float* row = base + (size_t)s * FEAT_;
    float4 x0 = *(const float4*)(row + lane * 4);
    float4 x1 = *(const float4*)(row + 256 + lane * 4);
    float p = dot8(x0, x1, v0, v1);
#pragma unroll
    for (int off = 32; off; off >>= 1) p += __shfl_xor(p, off, 64);
    float mn = fmaxf(m, p);
    float sc = __expf(m - mn);
    float w = __expf(p - mn);
    l = fmaf(l, sc, w);
    a0.x = fmaf(w, x0.x, a0.x * sc);
    a0.y = fmaf(w, x0.y, a0.y * sc);
    a0.z = fmaf(w, x0.z, a0.z * sc);
    a0.w = fmaf(w, x0.w, a0.w * sc);
    a1.x = fmaf(w, x1.x, a1.x * sc);
    a1.y = fmaf(w, x1.y, a1.y * sc);
    a1.z = fmaf(w, x1.z, a1.z * sc);
    a1.w = fmaf(w, x1.w, a1.w * sc);
    m = mn;
  }

  // cross-wave combine in LDS
  __shared__ float sm[4], sl[4];
  __shared__ float sa[4][FEAT_];
  if (lane == 0) { sm[wave] = m; sl[wave] = l; }
  *(float4*)&sa[wave][lane * 4] = a0;
  *(float4*)&sa[wave][256 + lane * 4] = a1;
  __syncthreads();

  float M = fmaxf(fmaxf(sm[0], sm[1]), fmaxf(sm[2], sm[3]));
  int idx = b * NSPLIT + split;
  if (M == -INFINITY) {  // no active rows in this split (uniform branch)
    if (tid == 0) { pm[idx] = -INFINITY; pl[idx] = 0.f; }
    for (int f = tid; f < FEAT_; f += 256) pacc[(size_t)idx * FEAT_ + f] = 0.f;
    return;
  }
  float e0 = __expf(sm[0] - M), e1 = __expf(sm[1] - M);
  float e2 = __expf(sm[2] - M), e3 = __expf(sm[3] - M);
  if (tid == 0) {
    pm[idx] = M;
    pl[idx] = e0 * sl[0] + e1 * sl[1] + e2 * sl[2] + e3 * sl[3];
  }
  for (int f = tid; f < FEAT_; f += 256)
    pacc[(size_t)idx * FEAT_ + f] =
        e0 * sa[0][f] + e1 * sa[1][f] + e2 * sa[2][f] + e3 * sa[3][f];
}

// ---------------------------------------------------------------------------
// Kernel 3: combine NSPLIT partials per batch, normalize, zero L==0 rows.
// ---------------------------------------------------------------------------
__global__ __launch_bounds__(256) void combine_kernel(
    const float* __restrict__ pm, const float* __restrict__ pl,
    const float* __restrict__ pacc, float* __restrict__ out) {
  int b = blockIdx.x;
  int tid = threadIdx.x;
  __shared__ float e[NSPLIT];
  __shared__ float inv_s;
  if (tid < NSPLIT) {  // NSPLIT == 32: lanes 0..31 of wave 0
    float mi = pm[b * NSPLIT + tid];
    float M = mi;
#pragma unroll
    for (int off = 16; off; off >>= 1) M = fmaxf(M, __shfl_xor(M, off, 64));
    float ei = (M == -INFINITY) ? 0.f : __expf(mi - M);
    e[tid] = ei;
    float lw = ei * pl[b * NSPLIT + tid];
#pragma unroll
    for (int off = 16; off; off >>= 1) lw += __shfl_xor(lw, off, 64);
    if (tid == 0) inv_s = (lw > 0.f) ? 1.f / lw : 0.f;  // L==0 -> zeros
  }
  __syncthreads();
  float inv = inv_s;
  for (int f = tid; f < FEAT_; f += 256) {
    float s = 0.f;
#pragma unroll
    for (int i = 0; i < NSPLIT; ++i)
      s = fmaf(e[i], pacc[((size_t)(b * NSPLIT + i)) * FEAT_ + f], s);
    out[b * FEAT_ + f] = s * inv;
  }
}

extern "C" void kernel_launch(void* const* d_in, const int* in_sizes, int n_in,
                              void* d_out, int out_size, void* d_ws, size_t ws_size,
                              hipStream_t stream) {
  const float* input_k = (const float*)d_in[0];
  const float* input_q = (const float*)d_in[1];
  const int*   ctx     = (const int*)d_in[2];
  const float* W_K     = (const float*)d_in[3];
  const float* W_Q     = (const float*)d_in[4];
  float* out = (float*)d_out;

  char* ws = (char*)d_ws;
  float* v    = (float*)ws;                                   // B*FEAT
  float* pm   = (float*)(ws + (size_t)B_ * FEAT_ * sizeof(float));
  float* pl   = pm + B_ * NSPLIT;
  float* pacc = pl + B_ * NSPLIT;                             // B*NSPLIT*FEAT

  qv_kernel<<<B_, 256, 0, stream>>>(input_q, W_Q, W_K, v);
  pass_kernel<<<dim3(NSPLIT, B_), 256, 0, stream>>>(input_k, ctx, v, pm, pl, pacc);
  combine_kernel<<<B_, 256, 0, stream>>>(pm, pl, pacc, out);
}